// Round 1
// baseline (1417.282 us; speedup 1.0000x reference)
//
#include <hip/hip_runtime.h>

#define N_NODES 50000
#define N_EDGES 800000
#define IN_CH 128
#define HIDDEN 16
#define OUT_CH 64

// ---------------------------------------------------------------------------
// Detect whether edge_index arrived as int64 (pairs of {low,0} words) or int32.
// Values are in [0, 50000) so if int64, every odd 32-bit word is 0.
// Probability of 64 consecutive odd words being 0 with real int32 indices ~ 0.
// ---------------------------------------------------------------------------
__global__ void k_detect(const int* __restrict__ ei, int* __restrict__ flag) {
    if (threadIdx.x == 0 && blockIdx.x == 0) {
        int is64 = 1;
        for (int i = 0; i < 64; ++i) {
            if (ei[2 * i + 1] != 0) { is64 = 0; break; }
        }
        *flag = is64;
    }
}

// ---------------------------------------------------------------------------
// y1 = x @ W1l, z1 = x @ W1r   (both [N, 16])
// 32 nodes per block, x tile + both weight mats staged in LDS.
// ---------------------------------------------------------------------------
__global__ __launch_bounds__(256) void k_linear1(
    const float* __restrict__ x,
    const float* __restrict__ W1l, const float* __restrict__ W1r,
    float* __restrict__ y1, float* __restrict__ z1)
{
    __shared__ float sW[IN_CH][32];        // cols 0-15: W1l, 16-31: W1r
    __shared__ float sx[32][IN_CH + 1];    // +1 pad -> conflict-free column reads
    const int t = threadIdx.x;

    for (int i = t; i < IN_CH * HIDDEN; i += 256) {
        int k = i / HIDDEN, c = i % HIDDEN;
        sW[k][c]      = W1l[i];
        sW[k][c + 16] = W1r[i];
    }

    const int node0 = blockIdx.x * 32;
    // coalesced float4 tile load: 32 rows x 32 float4
    for (int i = t; i < 32 * (IN_CH / 4); i += 256) {
        int row  = i / (IN_CH / 4);
        int col4 = i % (IN_CH / 4);
        int node = node0 + row;
        float4 v = make_float4(0.f, 0.f, 0.f, 0.f);
        if (node < N_NODES)
            v = ((const float4*)x)[node * (IN_CH / 4) + col4];
        sx[row][col4 * 4 + 0] = v.x;
        sx[row][col4 * 4 + 1] = v.y;
        sx[row][col4 * 4 + 2] = v.z;
        sx[row][col4 * 4 + 3] = v.w;
    }
    __syncthreads();

    const int row = t & 31;     // node within tile
    const int og  = t >> 5;     // output group 0..7 (4 outputs each)
    const int node = node0 + row;

    float acc[4] = {0.f, 0.f, 0.f, 0.f};
    for (int k = 0; k < IN_CH; ++k) {
        float xv = sx[row][k];
        #pragma unroll
        for (int j = 0; j < 4; ++j)
            acc[j] += xv * sW[k][og * 4 + j];
    }

    if (node < N_NODES) {
        #pragma unroll
        for (int j = 0; j < 4; ++j) {
            int oc = og * 4 + j;
            if (oc < HIDDEN) y1[node * HIDDEN + oc]            = acc[j];
            else             z1[node * HIDDEN + (oc - HIDDEN)] = acc[j];
        }
    }
}

// ---------------------------------------------------------------------------
// Edge scatter: agg[dst] += v[src] (16 ch), optional deg count.
// ---------------------------------------------------------------------------
__global__ __launch_bounds__(256) void k_agg(
    const int* __restrict__ ei,
    const float* __restrict__ v,
    float* __restrict__ agg,
    float* __restrict__ deg,
    const int* __restrict__ flag)
{
    const int e = blockIdx.x * 256 + threadIdx.x;
    if (e >= N_EDGES) return;
    const int is64 = *flag;
    int src, dst;
    if (is64) {
        src = ei[2 * e];
        dst = ei[2 * (N_EDGES + e)];
    } else {
        src = ei[e];
        dst = ei[N_EDGES + e];
    }
    if (deg) atomicAdd(&deg[dst], 1.0f);

    const float4* vp = (const float4*)(v + (size_t)src * HIDDEN);
    float4 a = vp[0], b = vp[1], c = vp[2], d = vp[3];
    float* ap = agg + (size_t)dst * HIDDEN;
    atomicAdd(ap + 0,  a.x); atomicAdd(ap + 1,  a.y);
    atomicAdd(ap + 2,  a.z); atomicAdd(ap + 3,  a.w);
    atomicAdd(ap + 4,  b.x); atomicAdd(ap + 5,  b.y);
    atomicAdd(ap + 6,  b.z); atomicAdd(ap + 7,  b.w);
    atomicAdd(ap + 8,  c.x); atomicAdd(ap + 9,  c.y);
    atomicAdd(ap + 10, c.z); atomicAdd(ap + 11, c.w);
    atomicAdd(ap + 12, d.x); atomicAdd(ap + 13, d.y);
    atomicAdd(ap + 14, d.z); atomicAdd(ap + 15, d.w);
}

// ---------------------------------------------------------------------------
// h = relu(agg1 / max(deg,1) + b1l + z1)
// ---------------------------------------------------------------------------
__global__ __launch_bounds__(256) void k_h(
    const float* __restrict__ agg1, const float* __restrict__ z1,
    const float* __restrict__ deg,  const float* __restrict__ b1l,
    float* __restrict__ h)
{
    const int idx = blockIdx.x * 256 + threadIdx.x;
    if (idx >= N_NODES * HIDDEN) return;
    const int n = idx / HIDDEN;
    const int c = idx % HIDDEN;
    float d = fmaxf(deg[n], 1.0f);
    float val = agg1[idx] / d + b1l[c] + z1[idx];
    h[idx] = fmaxf(val, 0.0f);
}

// ---------------------------------------------------------------------------
// out = log_softmax((agg2/deg) @ W2l + b2l + h @ W2r)
// one wave per node; lane == output channel (OUT_CH == 64 == wave size)
// ---------------------------------------------------------------------------
__global__ __launch_bounds__(256) void k_out(
    const float* __restrict__ agg2, const float* __restrict__ h,
    const float* __restrict__ deg,
    const float* __restrict__ W2l, const float* __restrict__ b2l,
    const float* __restrict__ W2r,
    float* __restrict__ out)
{
    __shared__ float sW[HIDDEN][2][OUT_CH];   // 8 KiB
    const int t = threadIdx.x;
    for (int i = t; i < HIDDEN * OUT_CH; i += 256) {
        int k = i / OUT_CH, c = i % OUT_CH;
        sW[k][0][c] = W2l[i];
        sW[k][1][c] = W2r[i];
    }
    __syncthreads();

    const int wave = t >> 6;
    const int lane = t & 63;
    const int n = blockIdx.x * 4 + wave;
    if (n >= N_NODES) return;

    const float inv = 1.0f / fmaxf(deg[n], 1.0f);
    const float* ap = agg2 + (size_t)n * HIDDEN;
    const float* hp = h    + (size_t)n * HIDDEN;

    float acc = b2l[lane];
    #pragma unroll
    for (int k = 0; k < HIDDEN; ++k) {
        float m  = ap[k] * inv;
        float hv = hp[k];
        acc += m * sW[k][0][lane] + hv * sW[k][1][lane];
    }

    // log-softmax across the 64 lanes
    float mx = acc;
    #pragma unroll
    for (int off = 32; off > 0; off >>= 1)
        mx = fmaxf(mx, __shfl_xor(mx, off));
    float ex = expf(acc - mx);
    float sum = ex;
    #pragma unroll
    for (int off = 32; off > 0; off >>= 1)
        sum += __shfl_xor(sum, off);

    out[(size_t)n * OUT_CH + lane] = acc - mx - logf(sum);
}

// ---------------------------------------------------------------------------
extern "C" void kernel_launch(void* const* d_in, const int* in_sizes, int n_in,
                              void* d_out, int out_size, void* d_ws, size_t ws_size,
                              hipStream_t stream)
{
    const float* x   = (const float*)d_in[0];
    const float* W1l = (const float*)d_in[1];
    const float* b1l = (const float*)d_in[2];
    const float* W1r = (const float*)d_in[3];
    const float* W2l = (const float*)d_in[4];
    const float* b2l = (const float*)d_in[5];
    const float* W2r = (const float*)d_in[6];
    const int*   ei  = (const int*)d_in[7];
    float* out = (float*)d_out;

    const size_t NH = (size_t)N_NODES * HIDDEN;   // 800000
    float* bufA = (float*)d_ws;          // y1, later h
    float* bufB = bufA + NH;             // z1
    float* bufC = bufB + NH;             // agg1, later agg2
    float* deg  = bufC + NH;             // [N_NODES]
    int*   flag = (int*)(deg + N_NODES);

    // zero accumulators (stream-ordered; graph-capture safe)
    hipMemsetAsync(bufC, 0, NH * sizeof(float), stream);
    hipMemsetAsync(deg,  0, N_NODES * sizeof(float), stream);

    k_detect<<<1, 64, 0, stream>>>(ei, flag);

    k_linear1<<<(N_NODES + 31) / 32, 256, 0, stream>>>(x, W1l, W1r, bufA, bufB);

    // agg1 = segment_sum(y1[src]) ; deg = segment_sum(1)
    k_agg<<<(N_EDGES + 255) / 256, 256, 0, stream>>>(ei, bufA, bufC, deg, flag);

    // h = relu(agg1/deg + b1 + z1)  -> overwrite bufA (y1 is dead)
    k_h<<<((int)NH + 255) / 256, 256, 0, stream>>>(bufC, bufB, deg, b1l, bufA);

    // re-zero accumulator for layer 2 (stream-ordered after k_h)
    hipMemsetAsync(bufC, 0, NH * sizeof(float), stream);

    // agg2 = segment_sum(h[src])
    k_agg<<<(N_EDGES + 255) / 256, 256, 0, stream>>>(ei, bufA, bufC, nullptr, flag);

    k_out<<<(N_NODES + 3) / 4, 256, 0, stream>>>(bufC, bufA, deg, W2l, b2l, W2r, out);
}

// Round 2
// 314.579 us; speedup vs baseline: 4.5053x; 4.5053x over previous
//
#include <hip/hip_runtime.h>

#define N_NODES 50000
#define N_EDGES 800000
#define IN_CH 128
#define HIDDEN 16
#define OUT_CH 64

// ---------------------------------------------------------------------------
// Detect whether edge_index arrived as int64 (pairs of {low,0} words) or int32.
// Values are in [0, 50000) so if int64, every odd 32-bit word is 0.
// ---------------------------------------------------------------------------
__global__ void k_detect(const int* __restrict__ ei, int* __restrict__ flag) {
    if (threadIdx.x == 0 && blockIdx.x == 0) {
        int is64 = 1;
        for (int i = 0; i < 64; ++i) {
            if (ei[2 * i + 1] != 0) { is64 = 0; break; }
        }
        *flag = is64;
    }
}

// ---------------------------------------------------------------------------
// Histogram of dst -> deg[] (int). 800k int atomics over 50k counters.
// ---------------------------------------------------------------------------
__global__ __launch_bounds__(256) void k_hist(
    const int* __restrict__ ei, int* __restrict__ deg, const int* __restrict__ flag)
{
    const int e = blockIdx.x * 256 + threadIdx.x;
    if (e >= N_EDGES) return;
    const int is64 = *flag;
    const int dst = is64 ? ei[2 * (N_EDGES + e)] : ei[N_EDGES + e];
    atomicAdd(&deg[dst], 1);
}

// ---------------------------------------------------------------------------
// Single-block exclusive scan of deg[50000] -> row_start[], cursor[] (copy).
// 1024 threads, 49 elements each serial + Hillis-Steele scan of partials.
// ---------------------------------------------------------------------------
__global__ __launch_bounds__(1024) void k_scan(
    const int* __restrict__ deg, int* __restrict__ row_start, int* __restrict__ cursor)
{
    __shared__ int part[1024];
    const int t = threadIdx.x;
    const int CH = (N_NODES + 1023) / 1024;   // 49
    const int base = t * CH;

    int s = 0;
    for (int i = 0; i < CH; ++i) {
        int idx = base + i;
        if (idx < N_NODES) s += deg[idx];
    }
    part[t] = s;
    __syncthreads();
    for (int off = 1; off < 1024; off <<= 1) {
        int v = (t >= off) ? part[t - off] : 0;
        __syncthreads();
        part[t] += v;
        __syncthreads();
    }
    int run = (t == 0) ? 0 : part[t - 1];   // exclusive prefix of my chunk
    for (int i = 0; i < CH; ++i) {
        int idx = base + i;
        if (idx < N_NODES) {
            row_start[idx] = run;
            cursor[idx]    = run;
            run += deg[idx];
        }
    }
}

// ---------------------------------------------------------------------------
// Bucket scatter: edge_src[pos] = src, pos = cursor[dst]++.
// ---------------------------------------------------------------------------
__global__ __launch_bounds__(256) void k_scatter(
    const int* __restrict__ ei, int* __restrict__ cursor,
    int* __restrict__ edge_src, const int* __restrict__ flag)
{
    const int e = blockIdx.x * 256 + threadIdx.x;
    if (e >= N_EDGES) return;
    const int is64 = *flag;
    int src, dst;
    if (is64) { src = ei[2 * e]; dst = ei[2 * (N_EDGES + e)]; }
    else      { src = ei[e];     dst = ei[N_EDGES + e]; }
    const int pos = atomicAdd(&cursor[dst], 1);
    edge_src[pos] = src;
}

// ---------------------------------------------------------------------------
// y1 = x @ W1l, z1 = x @ W1r   (both [N, 16])
// ---------------------------------------------------------------------------
__global__ __launch_bounds__(256) void k_linear1(
    const float* __restrict__ x,
    const float* __restrict__ W1l, const float* __restrict__ W1r,
    float* __restrict__ y1, float* __restrict__ z1)
{
    __shared__ float sW[IN_CH][32];        // cols 0-15: W1l, 16-31: W1r
    __shared__ float sx[32][IN_CH + 1];
    const int t = threadIdx.x;

    for (int i = t; i < IN_CH * HIDDEN; i += 256) {
        int k = i / HIDDEN, c = i % HIDDEN;
        sW[k][c]      = W1l[i];
        sW[k][c + 16] = W1r[i];
    }

    const int node0 = blockIdx.x * 32;
    for (int i = t; i < 32 * (IN_CH / 4); i += 256) {
        int row  = i / (IN_CH / 4);
        int col4 = i % (IN_CH / 4);
        int node = node0 + row;
        float4 v = make_float4(0.f, 0.f, 0.f, 0.f);
        if (node < N_NODES)
            v = ((const float4*)x)[node * (IN_CH / 4) + col4];
        sx[row][col4 * 4 + 0] = v.x;
        sx[row][col4 * 4 + 1] = v.y;
        sx[row][col4 * 4 + 2] = v.z;
        sx[row][col4 * 4 + 3] = v.w;
    }
    __syncthreads();

    const int row = t & 31;
    const int og  = t >> 5;
    const int node = node0 + row;

    float acc[4] = {0.f, 0.f, 0.f, 0.f};
    for (int k = 0; k < IN_CH; ++k) {
        float xv = sx[row][k];
        #pragma unroll
        for (int j = 0; j < 4; ++j)
            acc[j] += xv * sW[k][og * 4 + j];
    }

    if (node < N_NODES) {
        #pragma unroll
        for (int j = 0; j < 4; ++j) {
            int oc = og * 4 + j;
            if (oc < HIDDEN) y1[node * HIDDEN + oc]            = acc[j];
            else             z1[node * HIDDEN + (oc - HIDDEN)] = acc[j];
        }
    }
}

// ---------------------------------------------------------------------------
// Gather-aggregate layer 1, fused with h = relu(mean + b1 + z1).
// 16 lanes per node (lane = channel); each edge -> one 64B coalesced row read.
// ---------------------------------------------------------------------------
__global__ __launch_bounds__(256) void k_gather_h(
    const int* __restrict__ row_start, const int* __restrict__ deg,
    const int* __restrict__ edge_src,
    const float* __restrict__ y1, const float* __restrict__ z1,
    const float* __restrict__ b1l, float* __restrict__ h)
{
    const int g = threadIdx.x >> 4;      // node slot in block (0..15)
    const int c = threadIdx.x & 15;      // channel
    const int n = blockIdx.x * 16 + g;
    if (n >= N_NODES) return;

    const int beg = row_start[n];
    const int d   = deg[n];
    float s = 0.f;
    for (int i = 0; i < d; ++i) {
        const int src = edge_src[beg + i];            // broadcast across 16 lanes
        s += y1[(size_t)src * HIDDEN + c];            // 64B coalesced per edge
    }
    const float m = s / fmaxf((float)d, 1.0f);
    const float val = m + b1l[c] + z1[(size_t)n * HIDDEN + c];
    h[(size_t)n * HIDDEN + c] = fmaxf(val, 0.f);
}

// ---------------------------------------------------------------------------
// Gather-aggregate layer 2 -> mean2 (division fused).
// ---------------------------------------------------------------------------
__global__ __launch_bounds__(256) void k_gather_mean(
    const int* __restrict__ row_start, const int* __restrict__ deg,
    const int* __restrict__ edge_src,
    const float* __restrict__ h, float* __restrict__ mean2)
{
    const int g = threadIdx.x >> 4;
    const int c = threadIdx.x & 15;
    const int n = blockIdx.x * 16 + g;
    if (n >= N_NODES) return;

    const int beg = row_start[n];
    const int d   = deg[n];
    float s = 0.f;
    for (int i = 0; i < d; ++i) {
        const int src = edge_src[beg + i];
        s += h[(size_t)src * HIDDEN + c];
    }
    mean2[(size_t)n * HIDDEN + c] = s / fmaxf((float)d, 1.0f);
}

// ---------------------------------------------------------------------------
// out = log_softmax(mean2 @ W2l + b2l + h @ W2r)
// one wave per node; lane == output channel (OUT_CH == 64 == wave size)
// ---------------------------------------------------------------------------
__global__ __launch_bounds__(256) void k_out(
    const float* __restrict__ mean2, const float* __restrict__ h,
    const float* __restrict__ W2l, const float* __restrict__ b2l,
    const float* __restrict__ W2r,
    float* __restrict__ out)
{
    __shared__ float sW[HIDDEN][2][OUT_CH];   // 8 KiB
    const int t = threadIdx.x;
    for (int i = t; i < HIDDEN * OUT_CH; i += 256) {
        int k = i / OUT_CH, c = i % OUT_CH;
        sW[k][0][c] = W2l[i];
        sW[k][1][c] = W2r[i];
    }
    __syncthreads();

    const int wave = t >> 6;
    const int lane = t & 63;
    const int n = blockIdx.x * 4 + wave;
    if (n >= N_NODES) return;

    const float* ap = mean2 + (size_t)n * HIDDEN;
    const float* hp = h     + (size_t)n * HIDDEN;

    float acc = b2l[lane];
    #pragma unroll
    for (int k = 0; k < HIDDEN; ++k)
        acc += ap[k] * sW[k][0][lane] + hp[k] * sW[k][1][lane];

    float mx = acc;
    #pragma unroll
    for (int off = 32; off > 0; off >>= 1)
        mx = fmaxf(mx, __shfl_xor(mx, off));
    float ex = expf(acc - mx);
    float sum = ex;
    #pragma unroll
    for (int off = 32; off > 0; off >>= 1)
        sum += __shfl_xor(sum, off);

    out[(size_t)n * OUT_CH + lane] = acc - mx - logf(sum);
}

// ---------------------------------------------------------------------------
extern "C" void kernel_launch(void* const* d_in, const int* in_sizes, int n_in,
                              void* d_out, int out_size, void* d_ws, size_t ws_size,
                              hipStream_t stream)
{
    const float* x   = (const float*)d_in[0];
    const float* W1l = (const float*)d_in[1];
    const float* b1l = (const float*)d_in[2];
    const float* W1r = (const float*)d_in[3];
    const float* W2l = (const float*)d_in[4];
    const float* b2l = (const float*)d_in[5];
    const float* W2r = (const float*)d_in[6];
    const int*   ei  = (const int*)d_in[7];
    float* out = (float*)d_out;

    const size_t NH = (size_t)N_NODES * HIDDEN;   // 800000
    float* bufA     = (float*)d_ws;               // y1, later h
    float* bufB     = bufA + NH;                  // z1
    float* bufC     = bufB + NH;                  // mean2
    int* edge_src   = (int*)(bufC + NH);          // [N_EDGES]
    int* deg        = edge_src + N_EDGES;         // [N_NODES]
    int* row_start  = deg + N_NODES;              // [N_NODES]
    int* cursor     = row_start + N_NODES;        // [N_NODES]
    int* flag       = cursor + N_NODES;

    hipMemsetAsync(deg, 0, N_NODES * sizeof(int), stream);

    k_detect<<<1, 64, 0, stream>>>(ei, flag);

    // ---- CSR build (once, reused by both layers) ----
    const int EB = (N_EDGES + 255) / 256;
    k_hist<<<EB, 256, 0, stream>>>(ei, deg, flag);
    k_scan<<<1, 1024, 0, stream>>>(deg, row_start, cursor);
    k_scatter<<<EB, 256, 0, stream>>>(ei, cursor, edge_src, flag);

    // ---- layer 1 ----
    k_linear1<<<(N_NODES + 31) / 32, 256, 0, stream>>>(x, W1l, W1r, bufA, bufB);

    const int GB = (N_NODES + 15) / 16;
    k_gather_h<<<GB, 256, 0, stream>>>(row_start, deg, edge_src, bufA, bufB, b1l, bufB);
    // note: h written into bufB (z1 consumed in same kernel, per-element before write? no -
    // z1[n] is read by the same thread that writes h[n]; safe only because read happens
    // before write in-thread and no other thread touches that element.  (bufA=y1 must stay
    // intact during the gather since other nodes read it.)

    // ---- layer 2 ----
    k_gather_mean<<<GB, 256, 0, stream>>>(row_start, deg, edge_src, bufB, bufC);

    k_out<<<(N_NODES + 3) / 4, 256, 0, stream>>>(bufC, bufB, W2l, b2l, W2r, out);
}

// Round 3
// 198.914 us; speedup vs baseline: 7.1251x; 1.5815x over previous
//
#include <hip/hip_runtime.h>

#define N_NODES 50000
#define N_EDGES 800000
#define IN_CH 128
#define HIDDEN 16
#define OUT_CH 64

#define SCAN_BLK 1024
#define SCAN_NB ((N_NODES + SCAN_BLK - 1) / SCAN_BLK)   // 49

// ---------------------------------------------------------------------------
// Detect whether edge_index arrived as int64 (pairs of {low,0} words) or int32.
// ---------------------------------------------------------------------------
__global__ void k_detect(const int* __restrict__ ei, int* __restrict__ flag) {
    if (threadIdx.x == 0 && blockIdx.x == 0) {
        int is64 = 1;
        for (int i = 0; i < 64; ++i) {
            if (ei[2 * i + 1] != 0) { is64 = 0; break; }
        }
        *flag = is64;
    }
}

// ---------------------------------------------------------------------------
// Histogram of dst -> deg[] (int).
// ---------------------------------------------------------------------------
__global__ __launch_bounds__(256) void k_hist(
    const int* __restrict__ ei, int* __restrict__ deg, const int* __restrict__ flag)
{
    const int e = blockIdx.x * 256 + threadIdx.x;
    if (e >= N_EDGES) return;
    const int is64 = *flag;
    const int dst = is64 ? ei[2 * (N_EDGES + e)] : ei[N_EDGES + e];
    atomicAdd(&deg[dst], 1);
}

// ---------------------------------------------------------------------------
// Scan pass 1: per-block inclusive scan (wave shfl + LDS over 16 waves).
// row_start[i] = local exclusive prefix; bsum[blk] = block total.
// ---------------------------------------------------------------------------
__global__ __launch_bounds__(SCAN_BLK) void k_scan1(
    const int* __restrict__ deg, int* __restrict__ row_start, int* __restrict__ bsum)
{
    __shared__ int wsum[16];
    const int t = threadIdx.x;
    const int idx = blockIdx.x * SCAN_BLK + t;
    const int lane = t & 63;
    const int wid = t >> 6;

    int v = (idx < N_NODES) ? deg[idx] : 0;

    // inclusive scan within wave
    int inc = v;
    #pragma unroll
    for (int off = 1; off < 64; off <<= 1) {
        int u = __shfl_up(inc, off);
        if (lane >= off) inc += u;
    }
    if (lane == 63) wsum[wid] = inc;
    __syncthreads();

    if (wid == 0) {
        int w = (lane < 16) ? wsum[lane] : 0;
        #pragma unroll
        for (int off = 1; off < 16; off <<= 1) {
            int u = __shfl_up(w, off);
            if (lane >= off) w += u;
        }
        if (lane < 16) wsum[lane] = w;   // inclusive wave sums
    }
    __syncthreads();

    int wave_off = (wid == 0) ? 0 : wsum[wid - 1];
    int incl = inc + wave_off;
    if (idx < N_NODES) row_start[idx] = incl - v;   // local exclusive
    if (t == SCAN_BLK - 1) bsum[blockIdx.x] = incl;
}

// ---------------------------------------------------------------------------
// Scan pass 2: one wave scans SCAN_NB (49) block sums -> exclusive boffs.
// ---------------------------------------------------------------------------
__global__ __launch_bounds__(64) void k_scan2(
    const int* __restrict__ bsum, int* __restrict__ boffs)
{
    const int t = threadIdx.x;
    int v = (t < SCAN_NB) ? bsum[t] : 0;
    int inc = v;
    #pragma unroll
    for (int off = 1; off < 64; off <<= 1) {
        int u = __shfl_up(inc, off);
        if (t >= off) inc += u;
    }
    if (t < SCAN_NB) boffs[t] = inc - v;   // exclusive
}

// ---------------------------------------------------------------------------
// Scan pass 3: add block offset; emit final row_start and cursor copy.
// ---------------------------------------------------------------------------
__global__ __launch_bounds__(SCAN_BLK) void k_scan3(
    int* __restrict__ row_start, const int* __restrict__ boffs, int* __restrict__ cursor)
{
    const int idx = blockIdx.x * SCAN_BLK + threadIdx.x;
    if (idx >= N_NODES) return;
    const int r = row_start[idx] + boffs[blockIdx.x];
    row_start[idx] = r;
    cursor[idx] = r;
}

// ---------------------------------------------------------------------------
// Bucket scatter: edge_src[pos] = src, pos = cursor[dst]++.
// ---------------------------------------------------------------------------
__global__ __launch_bounds__(256) void k_scatter(
    const int* __restrict__ ei, int* __restrict__ cursor,
    int* __restrict__ edge_src, const int* __restrict__ flag)
{
    const int e = blockIdx.x * 256 + threadIdx.x;
    if (e >= N_EDGES) return;
    const int is64 = *flag;
    int src, dst;
    if (is64) { src = ei[2 * e]; dst = ei[2 * (N_EDGES + e)]; }
    else      { src = ei[e];     dst = ei[N_EDGES + e]; }
    const int pos = atomicAdd(&cursor[dst], 1);
    edge_src[pos] = src;
}

// ---------------------------------------------------------------------------
// y1 = x @ W1l, z1 = x @ W1r   (both [N, 16])
// ---------------------------------------------------------------------------
__global__ __launch_bounds__(256) void k_linear1(
    const float* __restrict__ x,
    const float* __restrict__ W1l, const float* __restrict__ W1r,
    float* __restrict__ y1, float* __restrict__ z1)
{
    __shared__ float sW[IN_CH][32];        // cols 0-15: W1l, 16-31: W1r
    __shared__ float sx[32][IN_CH + 1];
    const int t = threadIdx.x;

    for (int i = t; i < IN_CH * HIDDEN; i += 256) {
        int k = i / HIDDEN, c = i % HIDDEN;
        sW[k][c]      = W1l[i];
        sW[k][c + 16] = W1r[i];
    }

    const int node0 = blockIdx.x * 32;
    for (int i = t; i < 32 * (IN_CH / 4); i += 256) {
        int row  = i / (IN_CH / 4);
        int col4 = i % (IN_CH / 4);
        int node = node0 + row;
        float4 v = make_float4(0.f, 0.f, 0.f, 0.f);
        if (node < N_NODES)
            v = ((const float4*)x)[node * (IN_CH / 4) + col4];
        sx[row][col4 * 4 + 0] = v.x;
        sx[row][col4 * 4 + 1] = v.y;
        sx[row][col4 * 4 + 2] = v.z;
        sx[row][col4 * 4 + 3] = v.w;
    }
    __syncthreads();

    const int row = t & 31;
    const int og  = t >> 5;
    const int node = node0 + row;

    float acc[4] = {0.f, 0.f, 0.f, 0.f};
    for (int k = 0; k < IN_CH; ++k) {
        float xv = sx[row][k];
        #pragma unroll
        for (int j = 0; j < 4; ++j)
            acc[j] += xv * sW[k][og * 4 + j];
    }

    if (node < N_NODES) {
        #pragma unroll
        for (int j = 0; j < 4; ++j) {
            int oc = og * 4 + j;
            if (oc < HIDDEN) y1[node * HIDDEN + oc]            = acc[j];
            else             z1[node * HIDDEN + (oc - HIDDEN)] = acc[j];
        }
    }
}

// ---------------------------------------------------------------------------
// Gather-aggregate layer 1, fused with h = relu(mean + b1 + z1).
// 16 lanes per node (lane = channel); each edge -> one 64B coalesced row read.
// ---------------------------------------------------------------------------
__global__ __launch_bounds__(256) void k_gather_h(
    const int* __restrict__ row_start, const int* __restrict__ deg,
    const int* __restrict__ edge_src,
    const float* __restrict__ y1, const float* __restrict__ z1,
    const float* __restrict__ b1l, float* __restrict__ h)
{
    const int g = threadIdx.x >> 4;      // node slot in block (0..15)
    const int c = threadIdx.x & 15;      // channel
    const int n = blockIdx.x * 16 + g;
    if (n >= N_NODES) return;

    const int beg = row_start[n];
    const int d   = deg[n];
    float s = 0.f;
    for (int i = 0; i < d; ++i) {
        const int src = edge_src[beg + i];            // broadcast across 16 lanes
        s += y1[(size_t)src * HIDDEN + c];            // 64B coalesced per edge
    }
    const float m = s / fmaxf((float)d, 1.0f);
    const float val = m + b1l[c] + z1[(size_t)n * HIDDEN + c];
    h[(size_t)n * HIDDEN + c] = fmaxf(val, 0.f);
}

// ---------------------------------------------------------------------------
// Gather-aggregate layer 2 -> mean2 (division fused).
// ---------------------------------------------------------------------------
__global__ __launch_bounds__(256) void k_gather_mean(
    const int* __restrict__ row_start, const int* __restrict__ deg,
    const int* __restrict__ edge_src,
    const float* __restrict__ h, float* __restrict__ mean2)
{
    const int g = threadIdx.x >> 4;
    const int c = threadIdx.x & 15;
    const int n = blockIdx.x * 16 + g;
    if (n >= N_NODES) return;

    const int beg = row_start[n];
    const int d   = deg[n];
    float s = 0.f;
    for (int i = 0; i < d; ++i) {
        const int src = edge_src[beg + i];
        s += h[(size_t)src * HIDDEN + c];
    }
    mean2[(size_t)n * HIDDEN + c] = s / fmaxf((float)d, 1.0f);
}

// ---------------------------------------------------------------------------
// out = log_softmax(mean2 @ W2l + b2l + h @ W2r)
// ---------------------------------------------------------------------------
__global__ __launch_bounds__(256) void k_out(
    const float* __restrict__ mean2, const float* __restrict__ h,
    const float* __restrict__ W2l, const float* __restrict__ b2l,
    const float* __restrict__ W2r,
    float* __restrict__ out)
{
    __shared__ float sW[HIDDEN][2][OUT_CH];   // 8 KiB
    const int t = threadIdx.x;
    for (int i = t; i < HIDDEN * OUT_CH; i += 256) {
        int k = i / OUT_CH, c = i % OUT_CH;
        sW[k][0][c] = W2l[i];
        sW[k][1][c] = W2r[i];
    }
    __syncthreads();

    const int wave = t >> 6;
    const int lane = t & 63;
    const int n = blockIdx.x * 4 + wave;
    if (n >= N_NODES) return;

    const float* ap = mean2 + (size_t)n * HIDDEN;
    const float* hp = h     + (size_t)n * HIDDEN;

    float acc = b2l[lane];
    #pragma unroll
    for (int k = 0; k < HIDDEN; ++k)
        acc += ap[k] * sW[k][0][lane] + hp[k] * sW[k][1][lane];

    float mx = acc;
    #pragma unroll
    for (int off = 32; off > 0; off >>= 1)
        mx = fmaxf(mx, __shfl_xor(mx, off));
    float ex = expf(acc - mx);
    float sum = ex;
    #pragma unroll
    for (int off = 32; off > 0; off >>= 1)
        sum += __shfl_xor(sum, off);

    out[(size_t)n * OUT_CH + lane] = acc - mx - logf(sum);
}

// ---------------------------------------------------------------------------
extern "C" void kernel_launch(void* const* d_in, const int* in_sizes, int n_in,
                              void* d_out, int out_size, void* d_ws, size_t ws_size,
                              hipStream_t stream)
{
    const float* x   = (const float*)d_in[0];
    const float* W1l = (const float*)d_in[1];
    const float* b1l = (const float*)d_in[2];
    const float* W1r = (const float*)d_in[3];
    const float* W2l = (const float*)d_in[4];
    const float* b2l = (const float*)d_in[5];
    const float* W2r = (const float*)d_in[6];
    const int*   ei  = (const int*)d_in[7];
    float* out = (float*)d_out;

    const size_t NH = (size_t)N_NODES * HIDDEN;   // 800000
    float* bufA     = (float*)d_ws;               // y1, later h
    float* bufB     = bufA + NH;                  // z1, then h
    float* bufC     = bufB + NH;                  // mean2
    int* edge_src   = (int*)(bufC + NH);          // [N_EDGES]
    int* deg        = edge_src + N_EDGES;         // [N_NODES]
    int* row_start  = deg + N_NODES;              // [N_NODES]
    int* cursor     = row_start + N_NODES;        // [N_NODES]
    int* bsum       = cursor + N_NODES;           // [64]
    int* boffs      = bsum + 64;                  // [64]
    int* flag       = boffs + 64;

    hipMemsetAsync(deg, 0, N_NODES * sizeof(int), stream);

    k_detect<<<1, 64, 0, stream>>>(ei, flag);

    // ---- CSR build ----
    const int EB = (N_EDGES + 255) / 256;
    k_hist<<<EB, 256, 0, stream>>>(ei, deg, flag);
    k_scan1<<<SCAN_NB, SCAN_BLK, 0, stream>>>(deg, row_start, bsum);
    k_scan2<<<1, 64, 0, stream>>>(bsum, boffs);
    k_scan3<<<SCAN_NB, SCAN_BLK, 0, stream>>>(row_start, boffs, cursor);
    k_scatter<<<EB, 256, 0, stream>>>(ei, cursor, edge_src, flag);

    // ---- layer 1 ----
    k_linear1<<<(N_NODES + 31) / 32, 256, 0, stream>>>(x, W1l, W1r, bufA, bufB);

    const int GB = (N_NODES + 15) / 16;
    k_gather_h<<<GB, 256, 0, stream>>>(row_start, deg, edge_src, bufA, bufB, b1l, bufB);

    // ---- layer 2 ----
    k_gather_mean<<<GB, 256, 0, stream>>>(row_start, deg, edge_src, bufB, bufC);

    k_out<<<(N_NODES + 3) / 4, 256, 0, stream>>>(bufC, bufB, W2l, b2l, W2r, out);
}

// Round 4
// 160.250 us; speedup vs baseline: 8.8442x; 1.2413x over previous
//
#include <hip/hip_runtime.h>
#include <stdint.h>

#define N_NODES 50000
#define N_EDGES 800000
#define IN_CH 128
#define HIDDEN 16
#define OUT_CH 64

// ---------------------------------------------------------------------------
// Detect whether edge_index arrived as int64 (pairs of {low,0} words) or int32.
// ---------------------------------------------------------------------------
__global__ void k_detect(const int* __restrict__ ei, int* __restrict__ flag) {
    if (threadIdx.x == 0 && blockIdx.x == 0) {
        int is64 = 1;
        for (int i = 0; i < 64; ++i) {
            if (ei[2 * i + 1] != 0) { is64 = 0; break; }
        }
        *flag = is64;
    }
}

// ---------------------------------------------------------------------------
// Build per-dst linked lists in ONE pass, write-coalesced.
//   prev = atomicExch(&head[dst], e)           (random 4B atomics, 200KB table)
//   packed[e] = (uint64(prev) << 32) | src     (coalesced 8B store by edge id)
// head must be pre-set to -1 (0xFF memset).
// ---------------------------------------------------------------------------
__global__ __launch_bounds__(256) void k_link(
    const int* __restrict__ ei, int* __restrict__ head,
    uint64_t* __restrict__ packed, const int* __restrict__ flag)
{
    const int e = blockIdx.x * 256 + threadIdx.x;
    if (e >= N_EDGES) return;
    const int is64 = *flag;
    int src, dst;
    if (is64) { src = ei[2 * e]; dst = ei[2 * (N_EDGES + e)]; }
    else      { src = ei[e];     dst = ei[N_EDGES + e]; }
    const int prev = atomicExch(&head[dst], e);
    packed[e] = ((uint64_t)(uint32_t)prev << 32) | (uint32_t)src;
}

// ---------------------------------------------------------------------------
// y1 = x @ W1l, z1 = x @ W1r   (both [N, 16])
// ---------------------------------------------------------------------------
__global__ __launch_bounds__(256) void k_linear1(
    const float* __restrict__ x,
    const float* __restrict__ W1l, const float* __restrict__ W1r,
    float* __restrict__ y1, float* __restrict__ z1)
{
    __shared__ float sW[IN_CH][32];        // cols 0-15: W1l, 16-31: W1r
    __shared__ float sx[32][IN_CH + 1];
    const int t = threadIdx.x;

    for (int i = t; i < IN_CH * HIDDEN; i += 256) {
        int k = i / HIDDEN, c = i % HIDDEN;
        sW[k][c]      = W1l[i];
        sW[k][c + 16] = W1r[i];
    }

    const int node0 = blockIdx.x * 32;
    for (int i = t; i < 32 * (IN_CH / 4); i += 256) {
        int row  = i / (IN_CH / 4);
        int col4 = i % (IN_CH / 4);
        int node = node0 + row;
        float4 v = make_float4(0.f, 0.f, 0.f, 0.f);
        if (node < N_NODES)
            v = ((const float4*)x)[node * (IN_CH / 4) + col4];
        sx[row][col4 * 4 + 0] = v.x;
        sx[row][col4 * 4 + 1] = v.y;
        sx[row][col4 * 4 + 2] = v.z;
        sx[row][col4 * 4 + 3] = v.w;
    }
    __syncthreads();

    const int row = t & 31;
    const int og  = t >> 5;
    const int node = node0 + row;

    float acc[4] = {0.f, 0.f, 0.f, 0.f};
    for (int k = 0; k < IN_CH; ++k) {
        float xv = sx[row][k];
        #pragma unroll
        for (int j = 0; j < 4; ++j)
            acc[j] += xv * sW[k][og * 4 + j];
    }

    if (node < N_NODES) {
        #pragma unroll
        for (int j = 0; j < 4; ++j) {
            int oc = og * 4 + j;
            if (oc < HIDDEN) y1[node * HIDDEN + oc]            = acc[j];
            else             z1[node * HIDDEN + (oc - HIDDEN)] = acc[j];
        }
    }
}

// ---------------------------------------------------------------------------
// Gather-aggregate layer 1 via list walk, fused with h = relu(mean + b1 + z1).
// 16 lanes per node (lane = channel). Per step: one broadcast 8B packed read
// (critical path) + one coalesced 64B feature-row read (off critical path).
// Degree counted during the walk (no deg array).
// ---------------------------------------------------------------------------
__global__ __launch_bounds__(256) void k_gather_h(
    const int* __restrict__ head, const uint64_t* __restrict__ packed,
    const float* __restrict__ y1, const float* __restrict__ z1,
    const float* __restrict__ b1l, float* __restrict__ h)
{
    const int g = threadIdx.x >> 4;      // node slot in block (0..15)
    const int c = threadIdx.x & 15;      // channel
    const int n = blockIdx.x * 16 + g;
    if (n >= N_NODES) return;

    float s = 0.f;
    int d = 0;
    int e = head[n];
    while (e >= 0) {
        const uint64_t p = packed[e];              // broadcast across 16 lanes
        const int src = (int)(uint32_t)p;
        s += y1[(size_t)src * HIDDEN + c];         // 64B coalesced per edge
        ++d;
        e = (int)(p >> 32);
    }
    const float m = s / fmaxf((float)d, 1.0f);
    const float val = m + b1l[c] + z1[(size_t)n * HIDDEN + c];
    h[(size_t)n * HIDDEN + c] = fmaxf(val, 0.f);
}

// ---------------------------------------------------------------------------
// Gather-aggregate layer 2 via list walk -> mean2 (division fused).
// ---------------------------------------------------------------------------
__global__ __launch_bounds__(256) void k_gather_mean(
    const int* __restrict__ head, const uint64_t* __restrict__ packed,
    const float* __restrict__ h, float* __restrict__ mean2)
{
    const int g = threadIdx.x >> 4;
    const int c = threadIdx.x & 15;
    const int n = blockIdx.x * 16 + g;
    if (n >= N_NODES) return;

    float s = 0.f;
    int d = 0;
    int e = head[n];
    while (e >= 0) {
        const uint64_t p = packed[e];
        const int src = (int)(uint32_t)p;
        s += h[(size_t)src * HIDDEN + c];
        ++d;
        e = (int)(p >> 32);
    }
    mean2[(size_t)n * HIDDEN + c] = s / fmaxf((float)d, 1.0f);
}

// ---------------------------------------------------------------------------
// out = log_softmax(mean2 @ W2l + b2l + h @ W2r)
// one wave per node; lane == output channel (OUT_CH == 64 == wave size)
// ---------------------------------------------------------------------------
__global__ __launch_bounds__(256) void k_out(
    const float* __restrict__ mean2, const float* __restrict__ h,
    const float* __restrict__ W2l, const float* __restrict__ b2l,
    const float* __restrict__ W2r,
    float* __restrict__ out)
{
    __shared__ float sW[HIDDEN][2][OUT_CH];   // 8 KiB
    const int t = threadIdx.x;
    for (int i = t; i < HIDDEN * OUT_CH; i += 256) {
        int k = i / OUT_CH, c = i % OUT_CH;
        sW[k][0][c] = W2l[i];
        sW[k][1][c] = W2r[i];
    }
    __syncthreads();

    const int wave = t >> 6;
    const int lane = t & 63;
    const int n = blockIdx.x * 4 + wave;
    if (n >= N_NODES) return;

    const float* ap = mean2 + (size_t)n * HIDDEN;
    const float* hp = h     + (size_t)n * HIDDEN;

    float acc = b2l[lane];
    #pragma unroll
    for (int k = 0; k < HIDDEN; ++k)
        acc += ap[k] * sW[k][0][lane] + hp[k] * sW[k][1][lane];

    float mx = acc;
    #pragma unroll
    for (int off = 32; off > 0; off >>= 1)
        mx = fmaxf(mx, __shfl_xor(mx, off));
    float ex = expf(acc - mx);
    float sum = ex;
    #pragma unroll
    for (int off = 32; off > 0; off >>= 1)
        sum += __shfl_xor(sum, off);

    out[(size_t)n * OUT_CH + lane] = acc - mx - logf(sum);
}

// ---------------------------------------------------------------------------
extern "C" void kernel_launch(void* const* d_in, const int* in_sizes, int n_in,
                              void* d_out, int out_size, void* d_ws, size_t ws_size,
                              hipStream_t stream)
{
    const float* x   = (const float*)d_in[0];
    const float* W1l = (const float*)d_in[1];
    const float* b1l = (const float*)d_in[2];
    const float* W1r = (const float*)d_in[3];
    const float* W2l = (const float*)d_in[4];
    const float* b2l = (const float*)d_in[5];
    const float* W2r = (const float*)d_in[6];
    const int*   ei  = (const int*)d_in[7];
    float* out = (float*)d_out;

    const size_t NH = (size_t)N_NODES * HIDDEN;     // 800000
    uint64_t* packed = (uint64_t*)d_ws;             // [N_EDGES] 8B (aligned at base)
    float* bufA      = (float*)(packed + N_EDGES);  // y1, later mean2
    float* bufB      = bufA + NH;                   // z1, then h
    int* head        = (int*)(bufB + NH);           // [N_NODES]
    int* flag        = head + N_NODES;

    // head = -1 everywhere (0xFF bytes); stream-ordered, graph-capture safe
    hipMemsetAsync(head, 0xFF, N_NODES * sizeof(int), stream);

    k_detect<<<1, 64, 0, stream>>>(ei, flag);

    // ---- adjacency build: one pass, write-coalesced ----
    const int EB = (N_EDGES + 255) / 256;
    k_link<<<EB, 256, 0, stream>>>(ei, head, packed, flag);

    // ---- layer 1 ----
    k_linear1<<<(N_NODES + 31) / 32, 256, 0, stream>>>(x, W1l, W1r, bufA, bufB);

    const int GB = (N_NODES + 15) / 16;
    // h (into bufB; z1 read by same thread before write)
    k_gather_h<<<GB, 256, 0, stream>>>(head, packed, bufA, bufB, b1l, bufB);

    // ---- layer 2 ----  (mean2 overwrites bufA; y1 is dead)
    k_gather_mean<<<GB, 256, 0, stream>>>(head, packed, bufB, bufA);

    k_out<<<(N_NODES + 3) / 4, 256, 0, stream>>>(bufA, bufB, W2l, b2l, W2r, out);
}

// Round 5
// 158.191 us; speedup vs baseline: 8.9593x; 1.0130x over previous
//
#include <hip/hip_runtime.h>
#include <stdint.h>

#define N_NODES 50000
#define N_EDGES 800000
#define IN_CH 128
#define HIDDEN 16
#define OUT_CH 64

// ---------------------------------------------------------------------------
// head[] = -1 init + int64/int32 detect in one launch.
// Block 0 / thread 0 probes the first 64 odd words of edge_index: values are
// in [0,50000) so if int64, every odd 32-bit word is 0.
// ---------------------------------------------------------------------------
__global__ __launch_bounds__(256) void k_init(
    int* __restrict__ head, const int* __restrict__ ei, int* __restrict__ flag)
{
    const int i = blockIdx.x * 256 + threadIdx.x;
    if (i < N_NODES) head[i] = -1;
    if (i == 0) {
        int is64 = 1;
        for (int j = 0; j < 64; ++j) {
            if (ei[2 * j + 1] != 0) { is64 = 0; break; }
        }
        *flag = is64;
    }
}

// ---------------------------------------------------------------------------
// Build per-dst linked lists in ONE pass, write-coalesced.
//   prev = atomicExch(&head[dst], e)           (random 4B atomics, 200KB table)
//   packed[e] = (uint64(prev) << 32) | src     (coalesced 8B store by edge id)
// ---------------------------------------------------------------------------
__global__ __launch_bounds__(256) void k_link(
    const int* __restrict__ ei, int* __restrict__ head,
    uint64_t* __restrict__ packed, const int* __restrict__ flag)
{
    const int e = blockIdx.x * 256 + threadIdx.x;
    if (e >= N_EDGES) return;
    const int is64 = *flag;
    int src, dst;
    if (is64) { src = ei[2 * e]; dst = ei[2 * (N_EDGES + e)]; }
    else      { src = ei[e];     dst = ei[N_EDGES + e]; }
    const int prev = atomicExch(&head[dst], e);
    packed[e] = ((uint64_t)(uint32_t)prev << 32) | (uint32_t)src;
}

// ---------------------------------------------------------------------------
// y1 = x @ W1l, z1 = x @ W1r   (both [N, 16])
// ---------------------------------------------------------------------------
__global__ __launch_bounds__(256) void k_linear1(
    const float* __restrict__ x,
    const float* __restrict__ W1l, const float* __restrict__ W1r,
    float* __restrict__ y1, float* __restrict__ z1)
{
    __shared__ float sW[IN_CH][32];        // cols 0-15: W1l, 16-31: W1r
    __shared__ float sx[32][IN_CH + 1];
    const int t = threadIdx.x;

    for (int i = t; i < IN_CH * HIDDEN; i += 256) {
        int k = i / HIDDEN, c = i % HIDDEN;
        sW[k][c]      = W1l[i];
        sW[k][c + 16] = W1r[i];
    }

    const int node0 = blockIdx.x * 32;
    for (int i = t; i < 32 * (IN_CH / 4); i += 256) {
        int row  = i / (IN_CH / 4);
        int col4 = i % (IN_CH / 4);
        int node = node0 + row;
        float4 v = make_float4(0.f, 0.f, 0.f, 0.f);
        if (node < N_NODES)
            v = ((const float4*)x)[node * (IN_CH / 4) + col4];
        sx[row][col4 * 4 + 0] = v.x;
        sx[row][col4 * 4 + 1] = v.y;
        sx[row][col4 * 4 + 2] = v.z;
        sx[row][col4 * 4 + 3] = v.w;
    }
    __syncthreads();

    const int row = t & 31;
    const int og  = t >> 5;
    const int node = node0 + row;

    float acc[4] = {0.f, 0.f, 0.f, 0.f};
    for (int k = 0; k < IN_CH; ++k) {
        float xv = sx[row][k];
        #pragma unroll
        for (int j = 0; j < 4; ++j)
            acc[j] += xv * sW[k][og * 4 + j];
    }

    if (node < N_NODES) {
        #pragma unroll
        for (int j = 0; j < 4; ++j) {
            int oc = og * 4 + j;
            if (oc < HIDDEN) y1[node * HIDDEN + oc]            = acc[j];
            else             z1[node * HIDDEN + (oc - HIDDEN)] = acc[j];
        }
    }
}

// ---------------------------------------------------------------------------
// Gather-aggregate layer 1 via list walk, fused with h = relu(mean + b1 + z1).
// 16 lanes per node (lane = channel). Per step: one broadcast 8B packed read
// (critical path) + one coalesced 64B feature-row read (off critical path).
// ---------------------------------------------------------------------------
__global__ __launch_bounds__(256) void k_gather_h(
    const int* __restrict__ head, const uint64_t* __restrict__ packed,
    const float* __restrict__ y1, const float* __restrict__ z1,
    const float* __restrict__ b1l, float* __restrict__ h)
{
    const int g = threadIdx.x >> 4;      // node slot in block (0..15)
    const int c = threadIdx.x & 15;      // channel
    const int n = blockIdx.x * 16 + g;
    if (n >= N_NODES) return;

    float s = 0.f;
    int d = 0;
    int e = head[n];
    while (e >= 0) {
        const uint64_t p = packed[e];              // broadcast across 16 lanes
        const int src = (int)(uint32_t)p;
        s += y1[(size_t)src * HIDDEN + c];         // 64B coalesced per edge
        ++d;
        e = (int)(p >> 32);
    }
    const float m = s / fmaxf((float)d, 1.0f);
    const float val = m + b1l[c] + z1[(size_t)n * HIDDEN + c];
    h[(size_t)n * HIDDEN + c] = fmaxf(val, 0.f);
}

// ---------------------------------------------------------------------------
// Gather-aggregate layer 2 via list walk -> mean2 (division fused).
// ---------------------------------------------------------------------------
__global__ __launch_bounds__(256) void k_gather_mean(
    const int* __restrict__ head, const uint64_t* __restrict__ packed,
    const float* __restrict__ h, float* __restrict__ mean2)
{
    const int g = threadIdx.x >> 4;
    const int c = threadIdx.x & 15;
    const int n = blockIdx.x * 16 + g;
    if (n >= N_NODES) return;

    float s = 0.f;
    int d = 0;
    int e = head[n];
    while (e >= 0) {
        const uint64_t p = packed[e];
        const int src = (int)(uint32_t)p;
        s += h[(size_t)src * HIDDEN + c];
        ++d;
        e = (int)(p >> 32);
    }
    mean2[(size_t)n * HIDDEN + c] = s / fmaxf((float)d, 1.0f);
}

// ---------------------------------------------------------------------------
// out = log_softmax(mean2 @ W2l + b2l + h @ W2r)
// one wave per node; lane == output channel (OUT_CH == 64 == wave size)
// ---------------------------------------------------------------------------
__global__ __launch_bounds__(256) void k_out(
    const float* __restrict__ mean2, const float* __restrict__ h,
    const float* __restrict__ W2l, const float* __restrict__ b2l,
    const float* __restrict__ W2r,
    float* __restrict__ out)
{
    __shared__ float sW[HIDDEN][2][OUT_CH];   // 8 KiB
    const int t = threadIdx.x;
    for (int i = t; i < HIDDEN * OUT_CH; i += 256) {
        int k = i / OUT_CH, c = i % OUT_CH;
        sW[k][0][c] = W2l[i];
        sW[k][1][c] = W2r[i];
    }
    __syncthreads();

    const int wave = t >> 6;
    const int lane = t & 63;
    const int n = blockIdx.x * 4 + wave;
    if (n >= N_NODES) return;

    const float* ap = mean2 + (size_t)n * HIDDEN;
    const float* hp = h     + (size_t)n * HIDDEN;

    float acc = b2l[lane];
    #pragma unroll
    for (int k = 0; k < HIDDEN; ++k)
        acc += ap[k] * sW[k][0][lane] + hp[k] * sW[k][1][lane];

    float mx = acc;
    #pragma unroll
    for (int off = 32; off > 0; off >>= 1)
        mx = fmaxf(mx, __shfl_xor(mx, off));
    float ex = expf(acc - mx);
    float sum = ex;
    #pragma unroll
    for (int off = 32; off > 0; off >>= 1)
        sum += __shfl_xor(sum, off);

    out[(size_t)n * OUT_CH + lane] = acc - mx - logf(sum);
}

// ---------------------------------------------------------------------------
extern "C" void kernel_launch(void* const* d_in, const int* in_sizes, int n_in,
                              void* d_out, int out_size, void* d_ws, size_t ws_size,
                              hipStream_t stream)
{
    const float* x   = (const float*)d_in[0];
    const float* W1l = (const float*)d_in[1];
    const float* b1l = (const float*)d_in[2];
    const float* W1r = (const float*)d_in[3];
    const float* W2l = (const float*)d_in[4];
    const float* b2l = (const float*)d_in[5];
    const float* W2r = (const float*)d_in[6];
    const int*   ei  = (const int*)d_in[7];
    float* out = (float*)d_out;

    const size_t NH = (size_t)N_NODES * HIDDEN;     // 800000
    uint64_t* packed = (uint64_t*)d_ws;             // [N_EDGES] 8B (aligned at base)
    float* bufA      = (float*)(packed + N_EDGES);  // y1, later mean2
    float* bufB      = bufA + NH;                   // z1, then h
    int* head        = (int*)(bufB + NH);           // [N_NODES]
    int* flag        = head + N_NODES;

    // head = -1 + dtype detect, one custom launch (runtime fill kernel was 43us)
    k_init<<<(N_NODES + 255) / 256, 256, 0, stream>>>(head, ei, flag);

    // ---- adjacency build: one pass, write-coalesced ----
    const int EB = (N_EDGES + 255) / 256;
    k_link<<<EB, 256, 0, stream>>>(ei, head, packed, flag);

    // ---- layer 1 ----
    k_linear1<<<(N_NODES + 31) / 32, 256, 0, stream>>>(x, W1l, W1r, bufA, bufB);

    const int GB = (N_NODES + 15) / 16;
    // h (into bufB; z1 read by same thread before write)
    k_gather_h<<<GB, 256, 0, stream>>>(head, packed, bufA, bufB, b1l, bufB);

    // ---- layer 2 ----  (mean2 overwrites bufA; y1 is dead)
    k_gather_mean<<<GB, 256, 0, stream>>>(head, packed, bufB, bufA);

    k_out<<<(N_NODES + 3) / 4, 256, 0, stream>>>(bufA, bufB, W2l, b2l, W2r, out);
}

// Round 6
// 148.437 us; speedup vs baseline: 9.5481x; 1.0657x over previous
//
#include <hip/hip_runtime.h>
#include <stdint.h>

#define N_NODES 50000
#define N_EDGES 800000
#define IN_CH 128
#define HIDDEN 16
#define OUT_CH 64
#define NCHAIN 4

#define LB ((N_NODES + 31) / 32)        // 1563 linear1-role blocks
#define EB ((N_EDGES + 255) / 256)      // 3125 link-role blocks

// ---------------------------------------------------------------------------
// head[NCHAIN*N] = -1 init + int64/int32 detect in one launch.
// ---------------------------------------------------------------------------
__global__ __launch_bounds__(256) void k_init(
    int* __restrict__ head, const int* __restrict__ ei, int* __restrict__ flag)
{
    const int i = blockIdx.x * 256 + threadIdx.x;
    if (i < NCHAIN * N_NODES) head[i] = -1;
    if (i == 0) {
        int is64 = 1;
        for (int j = 0; j < 64; ++j) {
            if (ei[2 * j + 1] != 0) { is64 = 0; break; }
        }
        *flag = is64;
    }
}

// ---------------------------------------------------------------------------
// Fused: blocks [0,LB) compute y1 = x@W1l, z1 = x@W1r  (LDS-tiled);
//        blocks [LB,LB+EB) build 4-way-split per-dst linked lists:
//          prev = atomicExch(&head[(e&3)*N + dst], e)
//          packed[e] = (prev<<32) | src          (coalesced 8B store)
// The two roles stress different pipes (VALU/LDS vs atomic latency) and
// overlap across CUs instead of serializing on the stream.
// ---------------------------------------------------------------------------
__global__ __launch_bounds__(256) void k_build(
    const float* __restrict__ x,
    const float* __restrict__ W1l, const float* __restrict__ W1r,
    float* __restrict__ y1, float* __restrict__ z1,
    const int* __restrict__ ei, int* __restrict__ head,
    uint64_t* __restrict__ packed, const int* __restrict__ flag)
{
    __shared__ float sW[IN_CH][32];        // cols 0-15: W1l, 16-31: W1r
    __shared__ float sx[32][IN_CH + 1];
    const int t = threadIdx.x;

    if (blockIdx.x >= LB) {
        // ---- link role ----
        const int e = (blockIdx.x - LB) * 256 + t;
        if (e >= N_EDGES) return;
        const int is64 = *flag;
        int src, dst;
        if (is64) { src = ei[2 * e]; dst = ei[2 * (N_EDGES + e)]; }
        else      { src = ei[e];     dst = ei[N_EDGES + e]; }
        const int prev = atomicExch(&head[(e & (NCHAIN - 1)) * N_NODES + dst], e);
        packed[e] = ((uint64_t)(uint32_t)prev << 32) | (uint32_t)src;
        return;
    }

    // ---- linear1 role ----
    for (int i = t; i < IN_CH * HIDDEN; i += 256) {
        int k = i / HIDDEN, c = i % HIDDEN;
        sW[k][c]      = W1l[i];
        sW[k][c + 16] = W1r[i];
    }

    const int node0 = blockIdx.x * 32;
    for (int i = t; i < 32 * (IN_CH / 4); i += 256) {
        int row  = i / (IN_CH / 4);
        int col4 = i % (IN_CH / 4);
        int node = node0 + row;
        float4 v = make_float4(0.f, 0.f, 0.f, 0.f);
        if (node < N_NODES)
            v = ((const float4*)x)[node * (IN_CH / 4) + col4];
        sx[row][col4 * 4 + 0] = v.x;
        sx[row][col4 * 4 + 1] = v.y;
        sx[row][col4 * 4 + 2] = v.z;
        sx[row][col4 * 4 + 3] = v.w;
    }
    __syncthreads();

    const int row = t & 31;
    const int og  = t >> 5;
    const int node = node0 + row;

    float acc[4] = {0.f, 0.f, 0.f, 0.f};
    for (int k = 0; k < IN_CH; ++k) {
        float xv = sx[row][k];
        #pragma unroll
        for (int j = 0; j < 4; ++j)
            acc[j] += xv * sW[k][og * 4 + j];
    }

    if (node < N_NODES) {
        #pragma unroll
        for (int j = 0; j < 4; ++j) {
            int oc = og * 4 + j;
            if (oc < HIDDEN) y1[node * HIDDEN + oc]            = acc[j];
            else             z1[node * HIDDEN + (oc - HIDDEN)] = acc[j];
        }
    }
}

// ---------------------------------------------------------------------------
// Gather layer 1: one WAVE per node; 4 sub-groups of 16 lanes walk the 4
// chains in parallel (lane = g*16 + c). Cross-chain reduce via shfl_xor.
// Fused h = relu(mean + b1 + z1), written in place over z1.
// ---------------------------------------------------------------------------
__global__ __launch_bounds__(256) void k_gather_h(
    const int* __restrict__ head, const uint64_t* __restrict__ packed,
    const float* __restrict__ y1, float* __restrict__ z1h,
    const float* __restrict__ b1l)
{
    const int lane = threadIdx.x & 63;
    const int wid  = threadIdx.x >> 6;
    const int n = blockIdx.x * 4 + wid;     // 12500 blocks * 4 = exactly 50000
    const int g = lane >> 4;                // chain 0..3
    const int c = lane & 15;                // channel

    float s = 0.f;
    int d = 0;
    int e = head[g * N_NODES + n];
    while (e >= 0) {
        const uint64_t p = packed[e];                       // broadcast in group
        s += y1[(size_t)(uint32_t)(p & 0xFFFFFFFFu) * HIDDEN + c];
        ++d;
        e = (int)(p >> 32);
    }
    s += __shfl_xor(s, 16); s += __shfl_xor(s, 32);
    d += __shfl_xor(d, 16); d += __shfl_xor(d, 32);

    if (g == 0) {
        const float m = s / fmaxf((float)d, 1.0f);
        const size_t idx = (size_t)n * HIDDEN + c;
        z1h[idx] = fmaxf(m + b1l[c] + z1h[idx], 0.f);       // in-place z1 -> h
    }
}

// ---------------------------------------------------------------------------
// Fused gather layer 2 + output:
//   mean2 = chain-walk mean of h  (4 parallel chains, as above)
//   out   = log_softmax(mean2 @ W2l + b2l + h @ W2r)
// One wave per node; lane == output channel in the matmul phase.
// ---------------------------------------------------------------------------
__global__ __launch_bounds__(256) void k_out(
    const int* __restrict__ head, const uint64_t* __restrict__ packed,
    const float* __restrict__ h,
    const float* __restrict__ W2l, const float* __restrict__ b2l,
    const float* __restrict__ W2r,
    float* __restrict__ out)
{
    __shared__ float sW[HIDDEN][2][OUT_CH];   // 8 KiB
    __shared__ float sm[4][HIDDEN];           // mean2 per node slot
    __shared__ float sh[4][HIDDEN];           // h[n] per node slot
    const int t = threadIdx.x;
    for (int i = t; i < HIDDEN * OUT_CH; i += 256) {
        int k = i / OUT_CH, c = i % OUT_CH;
        sW[k][0][c] = W2l[i];
        sW[k][1][c] = W2r[i];
    }

    const int lane = t & 63;
    const int wid  = t >> 6;
    const int n = blockIdx.x * 4 + wid;       // exact: 12500*4 = 50000
    const int g = lane >> 4;
    const int c = lane & 15;

    float s = 0.f;
    int d = 0;
    int e = head[g * N_NODES + n];
    while (e >= 0) {
        const uint64_t p = packed[e];
        s += h[(size_t)(uint32_t)(p & 0xFFFFFFFFu) * HIDDEN + c];
        ++d;
        e = (int)(p >> 32);
    }
    s += __shfl_xor(s, 16); s += __shfl_xor(s, 32);
    d += __shfl_xor(d, 16); d += __shfl_xor(d, 32);
    if (g == 0) {
        sm[wid][c] = s / fmaxf((float)d, 1.0f);
        sh[wid][c] = h[(size_t)n * HIDDEN + c];
    }
    __syncthreads();

    float acc = b2l[lane];
    #pragma unroll
    for (int k = 0; k < HIDDEN; ++k)
        acc += sm[wid][k] * sW[k][0][lane] + sh[wid][k] * sW[k][1][lane];

    float mx = acc;
    #pragma unroll
    for (int off = 32; off > 0; off >>= 1)
        mx = fmaxf(mx, __shfl_xor(mx, off));
    float ex = expf(acc - mx);
    float sum = ex;
    #pragma unroll
    for (int off = 32; off > 0; off >>= 1)
        sum += __shfl_xor(sum, off);

    out[(size_t)n * OUT_CH + lane] = acc - mx - logf(sum);
}

// ---------------------------------------------------------------------------
extern "C" void kernel_launch(void* const* d_in, const int* in_sizes, int n_in,
                              void* d_out, int out_size, void* d_ws, size_t ws_size,
                              hipStream_t stream)
{
    const float* x   = (const float*)d_in[0];
    const float* W1l = (const float*)d_in[1];
    const float* b1l = (const float*)d_in[2];
    const float* W1r = (const float*)d_in[3];
    const float* W2l = (const float*)d_in[4];
    const float* b2l = (const float*)d_in[5];
    const float* W2r = (const float*)d_in[6];
    const int*   ei  = (const int*)d_in[7];
    float* out = (float*)d_out;

    const size_t NH = (size_t)N_NODES * HIDDEN;     // 800000
    uint64_t* packed = (uint64_t*)d_ws;             // [N_EDGES] 8B
    float* bufA      = (float*)(packed + N_EDGES);  // y1
    float* bufB      = bufA + NH;                   // z1 -> h (in place)
    int* head        = (int*)(bufB + NH);           // [NCHAIN * N_NODES]
    int* flag        = head + NCHAIN * N_NODES;

    k_init<<<(NCHAIN * N_NODES + 255) / 256, 256, 0, stream>>>(head, ei, flag);

    // fused: linear1 (blocks 0..LB-1)  +  list build (blocks LB..LB+EB-1)
    k_build<<<LB + EB, 256, 0, stream>>>(x, W1l, W1r, bufA, bufB, ei, head, packed, flag);

    // h = relu(mean(y1) + b1 + z1), in place over bufB
    k_gather_h<<<N_NODES / 4, 256, 0, stream>>>(head, packed, bufA, bufB, b1l);

    // fused gather2 + linear2 + log_softmax
    k_out<<<N_NODES / 4, 256, 0, stream>>>(head, packed, bufB, W2l, b2l, W2r, out);
}

// Round 7
// 140.618 us; speedup vs baseline: 10.0789x; 1.0556x over previous
//
#include <hip/hip_runtime.h>
#include <stdint.h>

#define N_NODES 50000
#define N_EDGES 800000
#define IN_CH 128
#define HIDDEN 16
#define OUT_CH 64
#define NCHAIN 8
#define GCAP 32                          // CSR slots per (node, lane-group)

#define LB ((N_NODES + 31) / 32)        // 1563 linear1-role blocks
#define EB ((N_EDGES + 255) / 256)      // 3125 link-role blocks

// ---------------------------------------------------------------------------
// head[NCHAIN*N] = -1 init + int64/int32 detect in one launch.
// ---------------------------------------------------------------------------
__global__ __launch_bounds__(256) void k_init(
    int* __restrict__ head, const int* __restrict__ ei, int* __restrict__ flag)
{
    const int i = blockIdx.x * 256 + threadIdx.x;
    if (i < NCHAIN * N_NODES) head[i] = -1;
    if (i == 0) {
        int is64 = 1;
        for (int j = 0; j < 64; ++j) {
            if (ei[2 * j + 1] != 0) { is64 = 0; break; }
        }
        *flag = is64;
    }
}

// ---------------------------------------------------------------------------
// Fused: blocks [0,LB) compute y1 = x@W1l, z1 = x@W1r  (LDS-tiled);
//        blocks [LB,LB+EB) build 8-way-split per-dst linked lists:
//          prev = atomicExch(&head[(e&7)*N + dst], e)
//          next[e] = prev (4B coalesced)  |  src16[e] = src (2B coalesced)
// next[] (3.2MB) is the only table on the walk critical path.
// ---------------------------------------------------------------------------
__global__ __launch_bounds__(256) void k_build(
    const float* __restrict__ x,
    const float* __restrict__ W1l, const float* __restrict__ W1r,
    float* __restrict__ y1, float* __restrict__ z1,
    const int* __restrict__ ei, int* __restrict__ head,
    int* __restrict__ next, uint16_t* __restrict__ src16,
    const int* __restrict__ flag)
{
    __shared__ float sW[IN_CH][32];        // cols 0-15: W1l, 16-31: W1r
    __shared__ float sx[32][IN_CH + 1];
    const int t = threadIdx.x;

    if (blockIdx.x >= LB) {
        // ---- link role ----
        const int e = (blockIdx.x - LB) * 256 + t;
        if (e >= N_EDGES) return;
        const int is64 = *flag;
        int src, dst;
        if (is64) { src = ei[2 * e]; dst = ei[2 * (N_EDGES + e)]; }
        else      { src = ei[e];     dst = ei[N_EDGES + e]; }
        const int prev = atomicExch(&head[(e & (NCHAIN - 1)) * N_NODES + dst], e);
        next[e]  = prev;
        src16[e] = (uint16_t)src;
        return;
    }

    // ---- linear1 role ----
    for (int i = t; i < IN_CH * HIDDEN; i += 256) {
        int k = i / HIDDEN, c = i % HIDDEN;
        sW[k][c]      = W1l[i];
        sW[k][c + 16] = W1r[i];
    }

    const int node0 = blockIdx.x * 32;
    for (int i = t; i < 32 * (IN_CH / 4); i += 256) {
        int row  = i / (IN_CH / 4);
        int col4 = i % (IN_CH / 4);
        int node = node0 + row;
        float4 v = make_float4(0.f, 0.f, 0.f, 0.f);
        if (node < N_NODES)
            v = ((const float4*)x)[node * (IN_CH / 4) + col4];
        sx[row][col4 * 4 + 0] = v.x;
        sx[row][col4 * 4 + 1] = v.y;
        sx[row][col4 * 4 + 2] = v.z;
        sx[row][col4 * 4 + 3] = v.w;
    }
    __syncthreads();

    const int row = t & 31;
    const int og  = t >> 5;
    const int node = node0 + row;

    float acc[4] = {0.f, 0.f, 0.f, 0.f};
    for (int k = 0; k < IN_CH; ++k) {
        float xv = sx[row][k];
        #pragma unroll
        for (int j = 0; j < 4; ++j)
            acc[j] += xv * sW[k][og * 4 + j];
    }

    if (node < N_NODES) {
        #pragma unroll
        for (int j = 0; j < 4; ++j) {
            int oc = og * 4 + j;
            if (oc < HIDDEN) y1[node * HIDDEN + oc]            = acc[j];
            else             z1[node * HIDDEN + (oc - HIDDEN)] = acc[j];
        }
    }
}

// ---------------------------------------------------------------------------
// Gather layer 1: one wave per node, 4 groups of 16 lanes; group g walks
// chains g and g+4 INTERLEAVED (2 outstanding loads per lane -> latency/2).
// While walking it EMITS a padded CSR row (<=GCAP srcs per group, ushort,
// written via lane rotation as coalesced 32B flushes) + cnt byte -> k_out
// never chain-walks. Fused h = relu(mean + b1 + z1) in place over z1.
// ---------------------------------------------------------------------------
__global__ __launch_bounds__(256) void k_gather_h(
    const int* __restrict__ head, const int* __restrict__ next,
    const uint16_t* __restrict__ src16,
    const float* __restrict__ y1, float* __restrict__ z1h,
    const float* __restrict__ b1l,
    uint16_t* __restrict__ row, unsigned char* __restrict__ cnt)
{
    const int lane = threadIdx.x & 63;
    const int wid  = threadIdx.x >> 6;
    const int n = blockIdx.x * 4 + wid;     // 12500 * 4 = exactly 50000
    const int g = lane >> 4;                // group 0..3
    const int c = lane & 15;                // channel / rotation slot

    const int base = (n * 4 + g) * GCAP;
    float s = 0.f;
    int kk = 0;
    unsigned int keep = 0;

    int e0 = head[g * N_NODES + n];
    int e1 = head[(g + 4) * N_NODES + n];

    while (e0 >= 0 && e1 >= 0) {
        const int n0 = next[e0], n1 = next[e1];          // independent
        const int s0 = src16[e0], s1 = src16[e1];        // independent
        s += y1[s0 * HIDDEN + c];
        s += y1[s1 * HIDDEN + c];
        if (kk < GCAP && (kk & 15) == c) keep = s0;
        ++kk;
        if (kk == 16 || kk == 32) row[base + kk - 16 + c] = (uint16_t)keep;
        if (kk < GCAP && (kk & 15) == c) keep = s1;
        ++kk;
        if (kk == 16 || kk == 32) row[base + kk - 16 + c] = (uint16_t)keep;
        e0 = n0; e1 = n1;
    }
    while (e0 >= 0) {
        const int n0 = next[e0];
        const int s0 = src16[e0];
        s += y1[s0 * HIDDEN + c];
        if (kk < GCAP && (kk & 15) == c) keep = s0;
        ++kk;
        if (kk == 16 || kk == 32) row[base + kk - 16 + c] = (uint16_t)keep;
        e0 = n0;
    }
    while (e1 >= 0) {
        const int n1 = next[e1];
        const int s1 = src16[e1];
        s += y1[s1 * HIDDEN + c];
        if (kk < GCAP && (kk & 15) == c) keep = s1;
        ++kk;
        if (kk == 16 || kk == 32) row[base + kk - 16 + c] = (uint16_t)keep;
        e1 = n1;
    }
    // tail flush of the partially-filled 16-chunk (only below GCAP)
    {
        const int off = kk & ~15;
        if (off < GCAP) {
            const int rem = kk - off;
            if (rem > 0 && c < rem) row[base + off + c] = (uint16_t)keep;
        }
    }
    if (c == 0) cnt[n * 4 + g] = (unsigned char)(kk > 255 ? 255 : kk);

    float st = s; int dt = kk;
    st += __shfl_xor(st, 16); st += __shfl_xor(st, 32);
    dt += __shfl_xor(dt, 16); dt += __shfl_xor(dt, 32);

    if (g == 0) {
        const float m = st / fmaxf((float)dt, 1.0f);
        const size_t idx = (size_t)n * HIDDEN + c;
        z1h[idx] = fmaxf(m + b1l[c] + z1h[idx], 0.f);   // in-place z1 -> h
    }
}

// ---------------------------------------------------------------------------
// Fused gather layer 2 + output, CSR-row based (no dependent chains):
//   group g broadcast-reads its <=GCAP srcs sequentially (2B, XCD-local),
//   issues 4-wide independent h-row gathers; chain-walk fallback if overflow.
//   Then out = log_softmax(mean2 @ W2l + b2l + h @ W2r), lane = out channel.
// ---------------------------------------------------------------------------
__global__ __launch_bounds__(256) void k_out(
    const unsigned char* __restrict__ cnt, const uint16_t* __restrict__ row,
    const int* __restrict__ head, const int* __restrict__ next,
    const uint16_t* __restrict__ src16,
    const float* __restrict__ h,
    const float* __restrict__ W2l, const float* __restrict__ b2l,
    const float* __restrict__ W2r,
    float* __restrict__ out)
{
    __shared__ float sW[HIDDEN][2][OUT_CH];   // 8 KiB
    __shared__ float sm[4][HIDDEN];
    __shared__ float sh[4][HIDDEN];
    const int t = threadIdx.x;
    for (int i = t; i < HIDDEN * OUT_CH; i += 256) {
        int k = i / OUT_CH, c2 = i % OUT_CH;
        sW[k][0][c2] = W2l[i];
        sW[k][1][c2] = W2r[i];
    }

    const int lane = t & 63;
    const int wid  = t >> 6;
    const int n = blockIdx.x * 4 + wid;
    const int g = lane >> 4;
    const int c = lane & 15;

    const int dg = cnt[n * 4 + g];
    const int base = (n * 4 + g) * GCAP;
    float s = 0.f;

    if (dg <= GCAP) {
        int i = 0;
        for (; i + 4 <= dg; i += 4) {
            const int s0 = row[base + i + 0];
            const int s1 = row[base + i + 1];
            const int s2 = row[base + i + 2];
            const int s3 = row[base + i + 3];
            s += h[s0 * HIDDEN + c] + h[s1 * HIDDEN + c]
               + h[s2 * HIDDEN + c] + h[s3 * HIDDEN + c];
        }
        for (; i < dg; ++i)
            s += h[(int)row[base + i] * HIDDEN + c];
    } else {
        // overflow fallback (P ~ e^-41): walk both chains
        int e0 = head[g * N_NODES + n];
        while (e0 >= 0) { s += h[(int)src16[e0] * HIDDEN + c]; e0 = next[e0]; }
        int e1 = head[(g + 4) * N_NODES + n];
        while (e1 >= 0) { s += h[(int)src16[e1] * HIDDEN + c]; e1 = next[e1]; }
    }

    float st = s; int dt = dg;
    st += __shfl_xor(st, 16); st += __shfl_xor(st, 32);
    dt += __shfl_xor(dt, 16); dt += __shfl_xor(dt, 32);
    if (g == 0) {
        sm[wid][c] = st / fmaxf((float)dt, 1.0f);
        sh[wid][c] = h[(size_t)n * HIDDEN + c];
    }
    __syncthreads();

    float acc = b2l[lane];
    #pragma unroll
    for (int k = 0; k < HIDDEN; ++k)
        acc += sm[wid][k] * sW[k][0][lane] + sh[wid][k] * sW[k][1][lane];

    float mx = acc;
    #pragma unroll
    for (int off = 32; off > 0; off >>= 1)
        mx = fmaxf(mx, __shfl_xor(mx, off));
    float ex = expf(acc - mx);
    float sum = ex;
    #pragma unroll
    for (int off = 32; off > 0; off >>= 1)
        sum += __shfl_xor(sum, off);

    out[(size_t)n * OUT_CH + lane] = acc - mx - logf(sum);
}

// ---------------------------------------------------------------------------
extern "C" void kernel_launch(void* const* d_in, const int* in_sizes, int n_in,
                              void* d_out, int out_size, void* d_ws, size_t ws_size,
                              hipStream_t stream)
{
    const float* x   = (const float*)d_in[0];
    const float* W1l = (const float*)d_in[1];
    const float* b1l = (const float*)d_in[2];
    const float* W1r = (const float*)d_in[3];
    const float* W2l = (const float*)d_in[4];
    const float* b2l = (const float*)d_in[5];
    const float* W2r = (const float*)d_in[6];
    const int*   ei  = (const int*)d_in[7];
    float* out = (float*)d_out;

    const size_t NH = (size_t)N_NODES * HIDDEN;     // 800000
    // 4B-aligned region first, then 2B/1B arrays. ws ~= 256MB (poison fills
    // in profile were 268MB), total use here ~26MB.
    int*   next   = (int*)d_ws;                     // [N_EDGES]      3.2 MB
    float* bufA   = (float*)(next + N_EDGES);       // y1             3.2 MB
    float* bufB   = bufA + NH;                      // z1 -> h        3.2 MB
    int*   head   = (int*)(bufB + NH);              // [8*N]          1.6 MB
    int*   flag   = head + NCHAIN * N_NODES;        // [1] (+pad)
    uint16_t* src16 = (uint16_t*)(flag + 2);        // [N_EDGES]      1.6 MB
    uint16_t* row   = src16 + N_EDGES;              // [N*4*GCAP]    12.8 MB
    unsigned char* cnt = (unsigned char*)(row + (size_t)N_NODES * 4 * GCAP); // 0.2 MB

    k_init<<<(NCHAIN * N_NODES + 255) / 256, 256, 0, stream>>>(head, ei, flag);

    // fused: linear1 (blocks 0..LB-1)  +  list build (blocks LB..LB+EB-1)
    k_build<<<LB + EB, 256, 0, stream>>>(x, W1l, W1r, bufA, bufB, ei, head,
                                         next, src16, flag);

    // h = relu(mean(y1)+b1+z1) in place over bufB; emits CSR rows + cnt
    k_gather_h<<<N_NODES / 4, 256, 0, stream>>>(head, next, src16, bufA, bufB,
                                                b1l, row, cnt);

    // fused gather2 (CSR) + linear2 + log_softmax
    k_out<<<N_NODES / 4, 256, 0, stream>>>(cnt, row, head, next, src16, bufB,
                                           W2l, b2l, W2r, out);
}